// Round 7
// baseline (714.952 us; speedup 1.0000x reference)
//
#include <hip/hip_runtime.h>
#include <math.h>

#define G 8192
#define D 1024
#define E 64
#define CAP 160
#define SLAB (E*CAP)                      // 10240 floats per token per tensor
#define OFF_COMB ((size_t)G*SLAB)         // 83886080
#define OFF_LOSS ((size_t)2*(size_t)G*SLAB)
#define OFF_M1 (OFF_LOSS+1)
#define OFF_M2 (OFF_M1+64)

typedef float vf4 __attribute__((ext_vector_type(4)));   // native vector for nt stores

// workspace element offsets (4B elements)
#define W_E1 0
#define W_E2 8192
#define W_G1 32768
#define W_G2 40960
#define W_SP  (49152+8192+64)             // 512 gating blocks * 64 floats
#define W_FLAG 131072                     // 512 per-gating-block done flags
#define MAGIC 0x13371337                  // != 0xAAAAAAAA poison, no reset needed

#define NGATE 512
#define NZERO 8192
#define NEPI  32

// ---------------- Single fused kernel ----------------
// grid 8736 x 256 thr:
//   [0,512):      gating GEMM+softmax+top2 (16 tokens/block); publishes done-flag
//   [512,8704):   nontemporal zero-fill of one token's dispatch+combine slabs (80 KB)
//   [8704,8736):  epilogue — acquire-polls the 512 flags, then rank/scan/scatter/loss.
// Epi blocks are LAST in dispatch order; zero blocks retire continuously, so gating
// blocks always become resident -> no deadlock. Epi runs in the zero-fill's shadow.
__global__ __launch_bounds__(256) void k_fused(const float* __restrict__ x,
                                               const float* __restrict__ w,
                                               int* __restrict__ wsi,
                                               float* __restrict__ wsf,
                                               float* __restrict__ out) {
  __shared__ float xs[16][64];
  __shared__ float sp[256];
  __shared__ int h1[32][64], h2[32][64];      // 16 KB: chunk x expert histograms (epi)
  __shared__ int hw1[4][64], hw2[4][64];
  __shared__ int base1_s[64], base2_s[64], c1k_s[64], run1_s[64], run2_s[64];
  __shared__ float spf[256];

  const int t = threadIdx.x;

  if (blockIdx.x >= NGATE && blockIdx.x < NGATE + NZERO) {
    // ---- zero path ----
    const int n = blockIdx.x - NGATE;
    vf4 z = {0.f, 0.f, 0.f, 0.f};
    vf4* __restrict__ dp = (vf4*)out + (size_t)n * (SLAB/4);
    vf4* __restrict__ cp = (vf4*)(out + OFF_COMB) + (size_t)n * (SLAB/4);
#pragma unroll
    for (int i = 0; i < 10; ++i) {
      const int idx = i * 256 + t;
      __builtin_nontemporal_store(z, &dp[idx]);
      __builtin_nontemporal_store(z, &cp[idx]);
    }
    return;
  }

  if (blockIdx.x < NGATE) {
    // ---- gating path ----
    const int lane = t & 63;
    const int wid  = t >> 6;
    const int nblk = blockIdx.x * 16;      // 16 tokens per block
    const int n0   = nblk + wid * 4;       // 4 tokens per wave

    float acc[4] = {0.f, 0.f, 0.f, 0.f};

    const int stok = t >> 4;               // 0..15 (staging token)
    const int sk   = (t & 15) * 4;         // 0..60 (staging k offset)
    const float* xsrc = x + (size_t)(nblk + stok) * D + sk;

    for (int kc = 0; kc < D; kc += 64) {
      *(float4*)&xs[stok][sk] = *(const float4*)(xsrc + kc);
      float wr[64];
#pragma unroll
      for (int j = 0; j < 64; ++j) wr[j] = w[(size_t)(kc + j) * E + lane];
      __syncthreads();
#pragma unroll
      for (int tt = 0; tt < 4; ++tt) {
        const int tok = wid * 4 + tt;
        float a = acc[tt];
#pragma unroll
        for (int j4 = 0; j4 < 16; ++j4) {
          const float4 xv = *(const float4*)&xs[tok][j4 * 4];   // broadcast b128
          a = fmaf(xv.x, wr[j4*4+0], a);
          a = fmaf(xv.y, wr[j4*4+1], a);
          a = fmaf(xv.z, wr[j4*4+2], a);
          a = fmaf(xv.w, wr[j4*4+3], a);
        }
        acc[tt] = a;
      }
      __syncthreads();
    }

    float ps = 0.f;
    for (int tt = 0; tt < 4; ++tt) {
      float v = acc[tt];
      // top-1 (stable: lowest index on ties, matches jax.lax.top_k)
      float m = v; int mi = lane;
      for (int off = 32; off > 0; off >>= 1) {
        float ov = __shfl_xor(m, off, 64);
        int   oi = __shfl_xor(mi, off, 64);
        if (ov > m || (ov == m && oi < mi)) { m = ov; mi = oi; }
      }
      // top-2
      float v2 = (lane == mi) ? -__builtin_inff() : v;
      float m2 = v2; int mi2 = lane;
      for (int off = 32; off > 0; off >>= 1) {
        float ov = __shfl_xor(m2, off, 64);
        int   oi = __shfl_xor(mi2, off, 64);
        if (ov > m2 || (ov == m2 && oi < mi2)) { m2 = ov; mi2 = oi; }
      }
      float ex = expf(v - m);
      float den = ex;
      for (int off = 32; off > 0; off >>= 1) den += __shfl_xor(den, off, 64);
      ps += ex / den;

      float g1 = 1.0f / den;            // exp(0)/den
      float g2 = expf(m2 - m) / den;
      float s  = g1 + g2 + 1e-9f;
      float ga = g1 / s, gb = g2 / s;
      if (lane == 0) {
        int n = n0 + tt;
        wsi[W_E1 + n] = mi;
        wsi[W_E2 + n] = mi2;
        wsf[W_G1 + n] = ga;
        wsf[W_G2 + n] = gb;
      }
    }
    sp[t] = ps;
    __syncthreads();
    if (t < 64) {
      wsf[W_SP + blockIdx.x * 64 + t] =
        sp[t] + sp[64 + t] + sp[128 + t] + sp[192 + t];
    }
    __syncthreads();
    if (t == 0) {
      __threadfence();   // publish all block writes device-wide
      __hip_atomic_store(&wsi[W_FLAG + blockIdx.x], MAGIC,
                         __ATOMIC_RELEASE, __HIP_MEMORY_SCOPE_AGENT);
    }
    return;
  }

  // ---- epilogue path (32 blocks, dispatched last) ----
  const int b = blockIdx.x - (NGATE + NZERO);   // chunk owned by this block
  const int lane = t & 63, wv = t >> 6;

  // wait for all gating blocks
  for (;;) {
    int done = 1;
    for (int i = t; i < NGATE; i += 256)
      if (__hip_atomic_load(&wsi[W_FLAG + i], __ATOMIC_ACQUIRE,
                            __HIP_MEMORY_SCOPE_AGENT) != MAGIC) done = 0;
    if (__syncthreads_and(done)) break;
    __builtin_amdgcn_s_sleep(2);
  }

  for (int i = t; i < 32 * 64; i += 256) { ((int*)h1)[i] = 0; ((int*)h2)[i] = 0; }
  if (t < 64) { for (int i = 0; i < 4; ++i) { hw1[i][t] = 0; hw2[i][t] = 0; } }
  __syncthreads();

  // all-chunk histograms (redundant per block — no cross-block communication)
  int my_e1 = 0, my_e2 = 0;
  for (int cc = 0; cc < 32; ++cc) {
    const int n = cc * 256 + t;
    const int a  = wsi[W_E1 + n];
    const int bb = wsi[W_E2 + n];
    if (cc == b) { my_e1 = a; my_e2 = bb; }
    atomicAdd(&h1[cc][a], 1);
    atomicAdd(&h2[cc][bb], 1);
  }
  __syncthreads();

  // per-expert totals + exclusive base at own chunk
  if (t < 64) {
    int r1 = 0, b1 = 0;
    for (int cc = 0; cc < 32; ++cc) { if (cc == b) b1 = r1; r1 += h1[cc][t]; }
    base1_s[t] = b1; run1_s[t] = r1; c1k_s[t] = min(r1, CAP);
  } else if (t < 128) {
    const int e = t - 64;
    int r2 = 0, b2 = 0;
    for (int cc = 0; cc < 32; ++cc) { if (cc == b) b2 = r2; r2 += h2[cc][e]; }
    base2_s[e] = b2; run2_s[e] = r2;
  }

  // intra-chunk ranks (wave shuffles + per-wave histograms)
  int c1 = 0, c2 = 0;
  for (int j = 0; j < 64; ++j) {
    int ja = __shfl(my_e1, j, 64);
    int jb = __shfl(my_e2, j, 64);
    if (j < lane) { c1 += (ja == my_e1); c2 += (jb == my_e2); }
  }
  atomicAdd(&hw1[wv][my_e1], 1);
  atomicAdd(&hw2[wv][my_e2], 1);
  __syncthreads();
  for (int ww = 0; ww < wv; ++ww) { c1 += hw1[ww][my_e1]; c2 += hw2[ww][my_e2]; }

  // scatter (slabs already zeroed by zero blocks... which may still be running
  // for OTHER tokens, but each token's slab is written by exactly one zero block
  // and one scatter thread; ordering between them matters!)
  const int n = b * 256 + t;
  const int p1 = base1_s[my_e1] + c1;
  const int p2 = base2_s[my_e2] + c2 + c1k_s[my_e2];
  const float g1 = wsf[W_G1 + n];
  const float g2 = wsf[W_G2 + n];
  const size_t base = (size_t)n * SLAB;
  // combine entry exists iff position < CAP and gate nonzero
  // (dispatch = (combine != 0), so g2 underflow-to-0 must kill dispatch too)
  if (p1 < CAP && g1 != 0.0f) {
    out[base + my_e1 * CAP + p1] = 1.0f;
    out[OFF_COMB + base + my_e1 * CAP + p1] = g1;
  }
  if (p2 < CAP && g2 != 0.0f) {
    out[base + my_e2 * CAP + p2] = 1.0f;
    out[OFF_COMB + base + my_e2 * CAP + p2] = g2;
  }

  if (b != 0) return;

  // counts
  if (t < 64) {
    out[OFF_M1 + t] = (float)c1k_s[t];
    out[OFF_M2 + t] = (float)min(run2_s[t], max(0, CAP - c1k_s[t]));
  }

  // loss = mean_e( (sumprob_e/8192) * (run1_e/8192) ) * 64^2
  {
    const int e = t & 63, q = t >> 6;
    float s = 0.f;
    for (int i = 0; i < 128; ++i)
      s += wsf[W_SP + (size_t)(q * 128 + i) * 64 + e];
    spf[t] = s;
  }
  __syncthreads();
  if (t < 64) {
    float s = spf[t] + spf[64 + t] + spf[128 + t] + spf[192 + t];
    float term = (s * (1.0f/8192.f)) * ((float)run1_s[t] * (1.0f/8192.f));
    for (int off = 32; off > 0; off >>= 1) term += __shfl_xor(term, off, 64);
    if (t == 0) out[OFF_LOSS] = (term * (1.0f/64.f)) * 4096.0f;
  }
}

extern "C" void kernel_launch(void* const* d_in, const int* in_sizes, int n_in,
                              void* d_out, int out_size, void* d_ws, size_t ws_size,
                              hipStream_t stream) {
  const float* x = (const float*)d_in[0];
  const float* w = (const float*)d_in[1];
  float* out = (float*)d_out;
  int*   wsi = (int*)d_ws;
  float* wsf = (float*)d_ws;

  k_fused<<<NGATE + NZERO + NEPI, 256, 0, stream>>>(x, w, wsi, wsf, out);
}